// Round 1
// baseline (90.309 us; speedup 1.0000x reference)
//
#include <hip/hip_runtime.h>
#include <stdint.h>

#define NUM_LEVELS 21
#define B 8
#define T 256
#define C 16
#define D 4096
#define DC 128        // d-outputs per block
#define COLS (DC + 3) // +3-column cyclic halo for the 4-gram diagonal

__global__ __launch_bounds__(256, 1)
void encoder_kernel(const float* __restrict__ x,
                    const float* __restrict__ lw,
                    const float* __restrict__ cw,
                    float* __restrict__ out) {
    __shared__ __align__(16) uint8_t idx_lds[T * C];   // 4 KB
    __shared__ uint32_t lwcol[COLS];                   // 21-bit sign words
    __shared__ uint32_t cwcol[COLS];                   // 16-bit sign words
    __shared__ int8_t  samp[T * COLS];                 // 33.5 KB, stride 131 (odd -> bank-friendly)
    __shared__ int     part[DC];

    const int tid = threadIdx.x;
    const int b  = blockIdx.x >> 5;
    const int d0 = (blockIdx.x & 31) << 7;

    // Phase 0a: idx = clip(rint(x/20*20), 0, 20)  -- exact replica of np ops in f32
    const float* xb = x + b * (T * C);
    #pragma unroll
    for (int k = 0; k < (T * C) / 256; ++k) {
        int i = tid + k * 256;
        float v  = xb[i];
        float fi = (v / 20.0f) * 20.0f;   // IEEE f32 div+mul, matches NumPy
        int id = (int)rintf(fi);          // half-to-even == np.round
        id = min(max(id, 0), NUM_LEVELS - 1);
        idx_lds[i] = (uint8_t)id;
    }

    // Phase 0b: bit-pack sign columns for our d-range (cyclic halo)
    if (tid < COLS) {
        int d = (d0 - 3 + tid) & (D - 1);
        uint32_t wl = 0;
        #pragma unroll
        for (int l = 0; l < NUM_LEVELS; ++l)
            wl |= (__float_as_uint(lw[l * D + d]) >> 31) << l;   // bit = (w < 0)
        lwcol[tid] = wl;
        uint32_t wc = 0;
        #pragma unroll
        for (int c = 0; c < C; ++c)
            wc |= (__float_as_uint(cw[c * D + d]) >> 31) << c;
        cwcol[tid] = wc;
    }
    __syncthreads();

    // Phase 1: one t per thread; samples[t][dr] = 16 - 2*popc(mask ^ cw16)  (exact int)
    {
        const int t = tid;
        const uint32_t* iw = (const uint32_t*)(idx_lds + t * C);
        uint32_t w0 = iw[0], w1 = iw[1], w2 = iw[2], w3 = iw[3];
        int l[16];
        #pragma unroll
        for (int c = 0; c < 4; ++c) {
            l[c]      = (w0 >> (8 * c)) & 31;
            l[4 + c]  = (w1 >> (8 * c)) & 31;
            l[8 + c]  = (w2 >> (8 * c)) & 31;
            l[12 + c] = (w3 >> (8 * c)) & 31;
        }
        for (int dr = 0; dr < COLS; ++dr) {
            uint32_t lc = lwcol[dr];   // broadcast read (same addr across lanes)
            uint32_t cc = cwcol[dr];
            uint32_t m = 0;
            #pragma unroll
            for (int c = 0; c < 16; ++c)
                m |= ((lc >> l[c]) & 1u) << c;
            int s = 16 - 2 * __popc(m ^ cc);
            samp[t * COLS + dr] = (int8_t)s;
        }
    }
    __syncthreads();

    // Phase 2: hv[d] = sum_t  s[t][j]*s[t+1][j+1]*s[t+2][j+2]*s[t+3][j+3], t-range split over 2 halves
    const int j    = tid & (DC - 1);
    const int half = tid >> 7;
    const int t0 = half ? 127 : 0;
    const int t1 = half ? 253 : 127;   // windows t = 0..252
    int acc = 0;
    const int8_t* sp = samp + j;
    for (int t = t0; t < t1; ++t) {
        int p = (int)sp[t * COLS]           * (int)sp[(t + 1) * COLS + 1]
              * (int)sp[(t + 2) * COLS + 2] * (int)sp[(t + 3) * COLS + 3];
        acc += p;
    }
    if (half) part[j] = acc;
    __syncthreads();
    if (!half) {
        int hv = acc + part[j];
        out[b * D + d0 + j] = hv > 0 ? 1.0f : -1.0f;   // hv==0 -> -1, matches reference
    }
}

extern "C" void kernel_launch(void* const* d_in, const int* in_sizes, int n_in,
                              void* d_out, int out_size, void* d_ws, size_t ws_size,
                              hipStream_t stream) {
    const float* x  = (const float*)d_in[0];
    const float* lw = (const float*)d_in[1];
    const float* cw = (const float*)d_in[2];
    float* out = (float*)d_out;
    dim3 grid(B * (D / DC));   // 256 blocks: (b, d-chunk)
    dim3 block(256);
    encoder_kernel<<<grid, block, 0, stream>>>(x, lw, cw, out);
}

// Round 3
// 75.067 us; speedup vs baseline: 1.2031x; 1.2031x over previous
//
#include <hip/hip_runtime.h>
#include <stdint.h>

#define NUM_LEVELS 21
#define BB 8
#define T 256
#define C 16
#define D 4096
#define DC 32            // d-outputs per block
#define COLS 35          // DC + 3 cyclic halo
#define IDX_STRIDE 20    // bytes per idx row (16 used + 4 pad -> bank spread)
#define QROWS 66         // 64 quads + 2 pad (B-reg overread at tail)
#define QSTRIDE 36       // u32 per quad row (35 used + 1 pad)

__global__ __launch_bounds__(256, 4)
void encoder_kernel(const float* __restrict__ x,
                    const float* __restrict__ lw,
                    const float* __restrict__ cw,
                    float* __restrict__ out) {
    __shared__ uint8_t  idx_lds[T * IDX_STRIDE];       // 5120 B
    __shared__ uint32_t lwcol[COLS], cwcol[COLS];
    __shared__ uint32_t sampQ[QROWS * QSTRIDE];        // 9504 B
    __shared__ int      part[8 * DC];

    const int tid   = threadIdx.x;
    const int b     = blockIdx.x >> 7;
    const int chunk = blockIdx.x & 127;
    const int d0    = chunk * DC;

    // ---- Phase 0a: idx = clip(rint(x/20*20), 0, 20); pack 4 bytes/u32 -> LDS
    const float* xb = x + b * (T * C);
    #pragma unroll
    for (int k = 0; k < 4; ++k) {
        int W = tid + k * 256;              // u32-word index 0..1023
        int t = W >> 2, m = W & 3;
        const float4 v = *(const float4*)(xb + t * C + 4 * m);
        float vv[4] = {v.x, v.y, v.z, v.w};
        uint32_t pk = 0;
        #pragma unroll
        for (int e = 0; e < 4; ++e) {
            float fi = (vv[e] / 20.0f) * 20.0f;   // exact replica of np ops
            int id = (int)rintf(fi);              // half-to-even == np.round
            id = min(max(id, 0), NUM_LEVELS - 1);
            pk |= (uint32_t)id << (8 * e);
        }
        *(uint32_t*)(idx_lds + t * IDX_STRIDE + 4 * m) = pk;
    }

    // ---- Phase 0b: bit-pack sign columns for our d-range (cyclic halo)
    if (tid < COLS) {
        int d = (d0 - 3 + tid) & (D - 1);
        uint32_t wl = 0;
        #pragma unroll
        for (int l = 0; l < NUM_LEVELS; ++l)
            wl |= (__float_as_uint(lw[l * D + d]) >> 31) << l;   // bit = (w<0)
        lwcol[tid] = wl;
        uint32_t wc = 0;
        #pragma unroll
        for (int c = 0; c < C; ++c)
            wc |= (__float_as_uint(cw[c * D + d]) >> 31) << c;
        cwcol[tid] = wc;
    }
    __syncthreads();

    // ---- Phase 1: thread = (quad q, colgroup g); 4 t's x 9 cols each.
    // s[t][col] = 16 - 2*popc(mask ^ cw16), packed 4 t-bytes per u32.
    {
        const int q = tid >> 2;             // 0..63
        const int g = tid & 3;              // 0..3
        uint32_t accum[9];
        #pragma unroll
        for (int k = 0; k < 9; ++k) accum[k] = 0;
        #pragma unroll
        for (int tp = 0; tp < 4; ++tp) {
            const int t = 4 * q + tp;
            const uint32_t* row = (const uint32_t*)(idx_lds + t * IDX_STRIDE);
            uint32_t w0 = row[0], w1 = row[1], w2 = row[2], w3 = row[3];
            int l[16];
            #pragma unroll
            for (int e = 0; e < 4; ++e) {
                l[e]      = (w0 >> (8 * e)) & 31;
                l[4 + e]  = (w1 >> (8 * e)) & 31;
                l[8 + e]  = (w2 >> (8 * e)) & 31;
                l[12 + e] = (w3 >> (8 * e)) & 31;
            }
            #pragma unroll
            for (int k = 0; k < 9; ++k) {
                int col = 9 * g + k; col = col > 34 ? 34 : col;  // clamp dup, benign
                uint32_t lc = lwcol[col], cc = cwcol[col];
                uint32_t m = 0;
                #pragma unroll
                for (int c = 0; c < 16; ++c)
                    m |= ((lc >> l[c]) & 1u) << c;
                int s = 16 - 2 * __popc(m ^ cc);
                accum[k] |= (uint32_t)(uint8_t)(int8_t)s << (8 * tp);
            }
        }
        #pragma unroll
        for (int k = 0; k < 9; ++k) {
            int col = 9 * g + k; col = col > 34 ? 34 : col;
            sampQ[q * QSTRIDE + col] = accum[k];
        }
    }
    __syncthreads();

    // ---- Phase 2: thread = (col j, seg); diagonal 4-gram product over t.
    // window t: prod_i s[t+i][j+i], sum over t.  Sliding 2-reg window/column.
    const int j   = tid & 31;
    const int seg = tid >> 5;
    int acc = 0;
    {
        const int t0 = seg * 32;
        const int t1 = (t0 + 32 < 253) ? t0 + 32 : 253;
        const int q0 = t0 >> 2;
        uint32_t A[4], Bv[4];
        #pragma unroll
        for (int i = 0; i < 4; ++i) {
            A[i]  = sampQ[q0 * QSTRIDE + j + i];
            Bv[i] = sampQ[(q0 + 1) * QSTRIDE + j + i];
        }
        for (int t = t0; t < t1; t += 4) {
            uint32_t pk0 = A[0];
            uint32_t pk1 = (A[1] >> 8)  | (Bv[1] << 24);
            uint32_t pk2 = (A[2] >> 16) | (Bv[2] << 16);
            uint32_t pk3 = (A[3] >> 24) | (Bv[3] << 8);
            #pragma unroll
            for (int k = 0; k < 4; ++k) {
                if (t + k < t1) {
                    int s0 = (int)(int8_t)(pk0 >> (8 * k));
                    int s1 = (int)(int8_t)(pk1 >> (8 * k));
                    int s2 = (int)(int8_t)(pk2 >> (8 * k));
                    int s3 = (int)(int8_t)(pk3 >> (8 * k));
                    acc += (s0 * s1) * (s2 * s3);
                }
            }
            const int qn = (t >> 2) + 2;
            #pragma unroll
            for (int i = 0; i < 4; ++i) {
                A[i]  = Bv[i];
                Bv[i] = sampQ[qn * QSTRIDE + j + i];   // tail overread hits pad row
            }
        }
    }
    if (seg) part[(seg - 1) * DC + j] = acc;
    __syncthreads();

    // ---- Final reduce + sign
    if (seg == 0) {
        int hv = acc;
        #pragma unroll
        for (int s = 0; s < 7; ++s) hv += part[s * DC + j];
        out[b * D + d0 + j] = hv > 0 ? 1.0f : -1.0f;
    }
}

extern "C" void kernel_launch(void* const* d_in, const int* in_sizes, int n_in,
                              void* d_out, int out_size, void* d_ws, size_t ws_size,
                              hipStream_t stream) {
    const float* x  = (const float*)d_in[0];
    const float* lw = (const float*)d_in[1];
    const float* cw = (const float*)d_in[2];
    float* out = (float*)d_out;
    dim3 grid(BB * (D / DC));   // 1024 blocks: (b, d-chunk of 32)
    dim3 block(256);
    encoder_kernel<<<grid, block, 0, stream>>>(x, lw, cw, out);
}